// Round 19
// baseline (208.179 us; speedup 1.0000x reference)
//
#include <hip/hip_runtime.h>
#include <hip/hip_bf16.h>
#include <stdint.h>

// Problem: B=4, T_p=T_f=16, S=256, D=2048, H=16, hd=128, T=64 tokens.
// Inputs f32; outputs f32. GEMMs in bf16 MFMA (f32 accumulate).
// R19 = R17/R18 resubmitted (three infra failures; R16 base verified):
// (a) mean with 8 accumulators / 32 loads in flight (2x MLP),
// (b) outputs video split to 8192 blocks (4 s-copies each),
// on top of R16's split-K-4 GEMMs + q-quarter attn.

using bf16x8v = __attribute__((ext_vector_type(8))) __bf16;
using f32x4v  = __attribute__((ext_vector_type(4))) float;

union Pack8 { __bf16 h[8]; uint4 u; };
union Pack4 { __bf16 h[4]; uint2 u; };

// Swizzled element offset in a [rows][64 bf16] LDS tile (GEMM):
__device__ __forceinline__ int swz(int r, int c) {
    return (r << 6) + ((c ^ (r & 7)) << 3);
}
// Swizzled float4-chunk offset in a [rows][128 f32] LDS tile (attn):
__device__ __forceinline__ int aswz(int r, int c) {
    return (r << 7) + ((c ^ (r & 31)) << 2);
}
__device__ __forceinline__ float4 f4sum4(const float* p0, const float* p1,
                                         const float* p2, const float* p3) {
    float4 a = *reinterpret_cast<const float4*>(p0);
    float4 b = *reinterpret_cast<const float4*>(p1);
    float4 c = *reinterpret_cast<const float4*>(p2);
    float4 d = *reinterpret_cast<const float4*>(p3);
    return {a.x + b.x + c.x + d.x, a.y + b.y + c.y + d.y,
            a.z + b.z + c.z + d.z, a.w + b.w + c.w + d.w};
}

// ---------------------------------------------------------------------------
// 0) Phase A, one launch (grid 4480):
//    blocks 0..255    : full-row mean -> tokens_bf rows 0..31 per batch
//                       (8 accumulators, 32 loads in flight)
//    blocks 256..383  : audio pack -> tokens_bf rows 32..63 per batch
//    blocks 384..4479 : transpose+convert W_qkv / W_proj -> bf16 [N][2048]
__global__ __launch_bounds__(256) void prep_all_kernel(
    const float* __restrict__ v_p, const float* __restrict__ v_f,
    const float* __restrict__ a_p, const float* __restrict__ a_f,
    const float* __restrict__ W_qkv, const float* __restrict__ W_proj,
    __bf16* __restrict__ tokens_bf,
    __bf16* __restrict__ Wt_qkv, __bf16* __restrict__ Wt_proj)
{
    __shared__ float Ls[64][68];
    int bid0 = blockIdx.x;
    if (bid0 < 256) {
        int which  = bid0 >> 7;         // 0: v_p, 1: v_f
        int row    = (bid0 >> 1) & 63;  // b*16 + t
        int dchunk = bid0 & 1;
        int d = (dchunk << 10) + (threadIdx.x << 2);
        const float* src = (which ? v_f : v_p) + ((size_t)row << 19) + d;
        float4 a0 = {0.f,0.f,0.f,0.f}, a1 = {0.f,0.f,0.f,0.f};
        float4 a2 = {0.f,0.f,0.f,0.f}, a3 = {0.f,0.f,0.f,0.f};
        float4 a4 = {0.f,0.f,0.f,0.f}, a5 = {0.f,0.f,0.f,0.f};
        float4 a6 = {0.f,0.f,0.f,0.f}, a7 = {0.f,0.f,0.f,0.f};
        #pragma unroll 4
        for (int s = 0; s < 256; s += 8) {
            float4 x0 = *reinterpret_cast<const float4*>(src + ((size_t)(s+0) << 11));
            float4 x1 = *reinterpret_cast<const float4*>(src + ((size_t)(s+1) << 11));
            float4 x2 = *reinterpret_cast<const float4*>(src + ((size_t)(s+2) << 11));
            float4 x3 = *reinterpret_cast<const float4*>(src + ((size_t)(s+3) << 11));
            float4 x4 = *reinterpret_cast<const float4*>(src + ((size_t)(s+4) << 11));
            float4 x5 = *reinterpret_cast<const float4*>(src + ((size_t)(s+5) << 11));
            float4 x6 = *reinterpret_cast<const float4*>(src + ((size_t)(s+6) << 11));
            float4 x7 = *reinterpret_cast<const float4*>(src + ((size_t)(s+7) << 11));
            a0.x += x0.x; a0.y += x0.y; a0.z += x0.z; a0.w += x0.w;
            a1.x += x1.x; a1.y += x1.y; a1.z += x1.z; a1.w += x1.w;
            a2.x += x2.x; a2.y += x2.y; a2.z += x2.z; a2.w += x2.w;
            a3.x += x3.x; a3.y += x3.y; a3.z += x3.z; a3.w += x3.w;
            a4.x += x4.x; a4.y += x4.y; a4.z += x4.z; a4.w += x4.w;
            a5.x += x5.x; a5.y += x5.y; a5.z += x5.z; a5.w += x5.w;
            a6.x += x6.x; a6.y += x6.y; a6.z += x6.z; a6.w += x6.w;
            a7.x += x7.x; a7.y += x7.y; a7.z += x7.z; a7.w += x7.w;
        }
        const float inv = 1.f / 256.f;
        float4 o;
        o.x = (((a0.x + a1.x) + (a2.x + a3.x)) + ((a4.x + a5.x) + (a6.x + a7.x))) * inv;
        o.y = (((a0.y + a1.y) + (a2.y + a3.y)) + ((a4.y + a5.y) + (a6.y + a7.y))) * inv;
        o.z = (((a0.z + a1.z) + (a2.z + a3.z)) + ((a4.z + a5.z) + (a6.z + a7.z))) * inv;
        o.w = (((a0.w + a1.w) + (a2.w + a3.w)) + ((a4.w + a5.w) + (a6.w + a7.w))) * inv;
        int b = row >> 4, tt = row & 15;
        int tokrow = b * 64 + which * 16 + tt;
        Pack4 p4;
        p4.h[0] = (__bf16)o.x; p4.h[1] = (__bf16)o.y;
        p4.h[2] = (__bf16)o.z; p4.h[3] = (__bf16)o.w;
        *reinterpret_cast<uint2*>(&tokens_bf[(size_t)tokrow * 2048 + d]) = p4.u;
    } else if (bid0 < 384) {
        int g = (bid0 - 256) * 256 + threadIdx.x;   // 8-elem group, 0..32767
        int which = g >> 14;
        int j = g & 16383;
        int b = j >> 12;
        int rr = j & 4095;
        int tt = rr >> 8;
        int gq = rr & 255;
        const float* src = (which ? a_f : a_p) + (size_t)(b * 16 + tt) * 2048 + gq * 8;
        float4 x0 = *reinterpret_cast<const float4*>(src);
        float4 x1 = *reinterpret_cast<const float4*>(src + 4);
        Pack8 p;
        p.h[0] = (__bf16)x0.x; p.h[1] = (__bf16)x0.y; p.h[2] = (__bf16)x0.z; p.h[3] = (__bf16)x0.w;
        p.h[4] = (__bf16)x1.x; p.h[5] = (__bf16)x1.y; p.h[6] = (__bf16)x1.z; p.h[7] = (__bf16)x1.w;
        int tokrow = b * 64 + 32 + which * 16 + tt;
        *reinterpret_cast<uint4*>(&tokens_bf[(size_t)tokrow * 2048 + gq * 8]) = p.u;
    } else {
        int bid = bid0 - 384;
        const float* src; __bf16* dst; int N, tile;
        if (bid < 3072) { src = W_qkv;  dst = Wt_qkv;  N = 6144; tile = bid; }
        else            { src = W_proj; dst = Wt_proj; N = 2048; tile = bid - 3072; }
        int tiles_n = N >> 6;
        int tn = tile % tiles_n;
        int tk = tile / tiles_n;
        int t = threadIdx.x;
        int rb = t >> 4;            // 0..15
        int c4 = (t & 15) << 2;     // 0..60
        #pragma unroll
        for (int s = 0; s < 4; ++s) {
            int r = rb + (s << 4);
            float4 v = *reinterpret_cast<const float4*>(
                src + (size_t)(tk * 64 + r) * N + tn * 64 + c4);
            *reinterpret_cast<float4*>(&Ls[r][c4]) = v;
        }
        __syncthreads();
        int c  = t >> 2;            // 0..63
        int r0 = (t & 3) << 4;      // 0,16,32,48
        Pack8 p0, p1;
        #pragma unroll
        for (int i = 0; i < 8; ++i) p0.h[i] = (__bf16)Ls[r0 + i][c];
        #pragma unroll
        for (int i = 0; i < 8; ++i) p1.h[i] = (__bf16)Ls[r0 + 8 + i][c];
        __bf16* drow = dst + (size_t)(tn * 64 + c) * 2048 + tk * 64 + r0;
        *reinterpret_cast<uint4*>(drow)     = p0.u;
        *reinterpret_cast<uint4*>(drow + 8) = p1.u;
    }
}

// ---------------------------------------------------------------------------
// 1) bf16 MFMA split-K GEMM (R16-verified), grid.z = 4 K-quarters (8 kt):
// Cpart[z][256][N] = A[:, z*512..] * Bt[:, z*512..]^T.
__global__ __launch_bounds__(256) void gemm_bf16_kernel(
    const __bf16* __restrict__ A, const __bf16* __restrict__ Bt,
    float* __restrict__ C, int N)
{
    __shared__ __bf16 As[4096];
    __shared__ __bf16 Bs[4096];
    const int t = threadIdx.x;
    const int m0 = blockIdx.y << 6;
    const int n0 = blockIdx.x << 6;
    const int kz = blockIdx.z;           // K-quarter 0..3
    const int kbase = kz << 9;           // element offset in K (512 each)
    const int lane = t & 63;
    const int w = t >> 6;                // wave 0..3
    const int wm = w << 4;               // wave's m offset
    const int lrow = lane & 15;
    const int lk = lane >> 4;            // 0..3
    const int srl = lane >> 3;           // 0..7
    const int schunk = lane & 7;

    f32x4v acc[4] = {{0.f,0.f,0.f,0.f},{0.f,0.f,0.f,0.f},
                     {0.f,0.f,0.f,0.f},{0.f,0.f,0.f,0.f}};

    int row_c0 = (w << 4) + srl;
    int row_c1 = row_c0 + 8;
    const __bf16* gA0 = A  + (size_t)(m0 + row_c0) * 2048 + kbase + ((schunk ^ (row_c0 & 7)) << 3);
    const __bf16* gA1 = A  + (size_t)(m0 + row_c1) * 2048 + kbase + ((schunk ^ (row_c1 & 7)) << 3);
    const __bf16* gB0 = Bt + (size_t)(n0 + row_c0) * 2048 + kbase + ((schunk ^ (row_c0 & 7)) << 3);
    const __bf16* gB1 = Bt + (size_t)(n0 + row_c1) * 2048 + kbase + ((schunk ^ (row_c1 & 7)) << 3);
    __bf16* lA0 = &As[(w << 4) << 6];
    __bf16* lA1 = &As[((w << 4) + 8) << 6];
    __bf16* lB0 = &Bs[(w << 4) << 6];
    __bf16* lB1 = &Bs[((w << 4) + 8) << 6];

    for (int kt = 0; kt < 8; ++kt) {
        __syncthreads();
        int ko = kt << 6;
        __builtin_amdgcn_global_load_lds(
            (const __attribute__((address_space(1))) void*)(gA0 + ko),
            (__attribute__((address_space(3))) void*)lA0, 16, 0, 0);
        __builtin_amdgcn_global_load_lds(
            (const __attribute__((address_space(1))) void*)(gA1 + ko),
            (__attribute__((address_space(3))) void*)lA1, 16, 0, 0);
        __builtin_amdgcn_global_load_lds(
            (const __attribute__((address_space(1))) void*)(gB0 + ko),
            (__attribute__((address_space(3))) void*)lB0, 16, 0, 0);
        __builtin_amdgcn_global_load_lds(
            (const __attribute__((address_space(1))) void*)(gB1 + ko),
            (__attribute__((address_space(3))) void*)lB1, 16, 0, 0);
        __syncthreads();
        #pragma unroll
        for (int s = 0; s < 2; ++s) {
            int cA = (s << 2) + lk;
            bf16x8v af = *reinterpret_cast<const bf16x8v*>(&As[swz(wm + lrow, cA)]);
            #pragma unroll
            for (int j = 0; j < 4; ++j) {
                bf16x8v bf = *reinterpret_cast<const bf16x8v*>(&Bs[swz((j << 4) + lrow, cA)]);
                acc[j] = __builtin_amdgcn_mfma_f32_16x16x32_bf16(af, bf, acc[j], 0, 0, 0);
            }
        }
    }
    float* Cz = C + (size_t)kz * 256 * N;
    #pragma unroll
    for (int j = 0; j < 4; ++j) {
        int col = n0 + (j << 4) + lrow;
        #pragma unroll
        for (int e = 0; e < 4; ++e) {
            int row = m0 + wm + (lk << 2) + e;
            Cz[(size_t)row * N + col] = acc[j][e];
        }
    }
}

// ---------------------------------------------------------------------------
// 2) Attention (R16-verified): block = (b, h, q-quarter of 16 rows), grid
// 256. Sums the FOUR qkv K-partials during staging, RoPE after sum; causal
// softmax; bf16 out. Static-indexed registers; uniform guards.
__global__ __launch_bounds__(256) void attn_kernel(
    const float* __restrict__ qkv, __bf16* __restrict__ attn_out)
{
    __shared__ float q_s[16 * 128];   // 8KB swizzled; reused as p_s[16][65]
    __shared__ float k_s[64 * 128];   // 32KB swizzled; reused as v_s
    const size_t PART = (size_t)256 * 6144;   // qkv partial stride
    int bid = blockIdx.x;
    int qt = bid & 3;                 // q-quarter
    int h  = (bid >> 2) & 15;
    int b  = bid >> 6;
    int tid = threadIdx.x;
    int qr0 = qt << 4;                // first q row of this block
    int kcap = qr0 + 16;              // causal K rows needed (16/32/48/64)
    const float* base0 = qkv + (size_t)(b * 64) * 6144 + h * 128;
    const float* base1 = base0 + PART;
    const float* base2 = base0 + 2 * PART;
    const float* base3 = base0 + 3 * PART;
    const float L2C = 0.20762050593046012f;   // log2(10000)/64
    const float scale = 0.0883883476483184405f;   // 128^-0.5

    {
        int tq = tid >> 4;            // local row 0..15
        int cg = tid & 15;            // low-half chunk
        int d = cg << 2;
        int grow = qr0 + tq;
        size_t ro = (size_t)grow * 6144;
        float4 q1 = f4sum4(base0 + ro + d, base1 + ro + d, base2 + ro + d, base3 + ro + d);
        float4 q2 = f4sum4(base0 + ro + d + 64, base1 + ro + d + 64,
                           base2 + ro + d + 64, base3 + ro + d + 64);
        float ft = (float)grow;
        float a0 = ft * exp2f(-(float)(d + 0) * L2C);
        float a1 = ft * exp2f(-(float)(d + 1) * L2C);
        float a2 = ft * exp2f(-(float)(d + 2) * L2C);
        float a3 = ft * exp2f(-(float)(d + 3) * L2C);
        float c0 = cosf(a0), s0f = sinf(a0);
        float c1 = cosf(a1), s1f = sinf(a1);
        float c2 = cosf(a2), s2f = sinf(a2);
        float c3 = cosf(a3), s3f = sinf(a3);
        float4 qa, qb;
        qa.x = q1.x * c0 - q2.x * s0f;  qb.x = q2.x * c0 + q1.x * s0f;
        qa.y = q1.y * c1 - q2.y * s1f;  qb.y = q2.y * c1 + q1.y * s1f;
        qa.z = q1.z * c2 - q2.z * s2f;  qb.z = q2.z * c2 + q1.z * s2f;
        qa.w = q1.w * c3 - q2.w * s3f;  qb.w = q2.w * c3 + q1.w * s3f;
        *reinterpret_cast<float4*>(&q_s[aswz(tq, cg)])      = qa;
        *reinterpret_cast<float4*>(&q_s[aswz(tq, cg + 16)]) = qb;
    }
    #pragma unroll
    for (int r = 0; r < 4; ++r) {
        int idx = tid + (r << 8);
        if (idx < (kcap << 4)) {
            int tk = idx >> 4;        // global k row
            int cg = idx & 15;
            int d = cg << 2;
            size_t ro = (size_t)tk * 6144 + 2048;
            float4 k1 = f4sum4(base0 + ro + d, base1 + ro + d, base2 + ro + d, base3 + ro + d);
            float4 k2 = f4sum4(base0 + ro + d + 64, base1 + ro + d + 64,
                               base2 + ro + d + 64, base3 + ro + d + 64);
            float ft = (float)tk;
            float a0 = ft * exp2f(-(float)(d + 0) * L2C);
            float a1 = ft * exp2f(-(float)(d + 1) * L2C);
            float a2 = ft * exp2f(-(float)(d + 2) * L2C);
            float a3 = ft * exp2f(-(float)(d + 3) * L2C);
            float c0 = cosf(a0), s0f = sinf(a0);
            float c1 = cosf(a1), s1f = sinf(a1);
            float c2 = cosf(a2), s2f = sinf(a2);
            float c3 = cosf(a3), s3f = sinf(a3);
            float4 ka, kb;
            ka.x = k1.x * c0 - k2.x * s0f;  kb.x = k2.x * c0 + k1.x * s0f;
            ka.y = k1.y * c1 - k2.y * s1f;  kb.y = k2.y * c1 + k1.y * s1f;
            ka.z = k1.z * c2 - k2.z * s2f;  kb.z = k2.z * c2 + k1.z * s2f;
            ka.w = k1.w * c3 - k2.w * s3f;  kb.w = k2.w * c3 + k1.w * s3f;
            *reinterpret_cast<float4*>(&k_s[aswz(tk, cg)])      = ka;
            *reinterpret_cast<float4*>(&k_s[aswz(tk, cg + 16)]) = kb;
        }
    }
    __syncthreads();
    int qi = tid >> 4;
    int g  = tid & 15;
    int qg = qr0 + qi;
    float pv[4] = {0.f, 0.f, 0.f, 0.f};
    for (int c = 0; c < 32; ++c) {
        float4 a = *reinterpret_cast<const float4*>(&q_s[aswz(qi, c)]);
        #pragma unroll
        for (int j = 0; j < 4; ++j) {
            if ((j << 4) < kcap) {
                int ki = (j << 4) + g;
                float4 bb = *reinterpret_cast<const float4*>(&k_s[aswz(ki, c)]);
                pv[j] += a.x * bb.x + a.y * bb.y + a.z * bb.z + a.w * bb.w;
            }
        }
    }
    float m = -1e30f;
    #pragma unroll
    for (int j = 0; j < 4; ++j) {
        if ((j << 4) < kcap) {
            int ki = (j << 4) + g;
            pv[j] = (ki <= qg) ? pv[j] * scale : -1e30f;
            m = fmaxf(m, pv[j]);
        }
    }
    m = fmaxf(m, __shfl_xor(m, 1));
    m = fmaxf(m, __shfl_xor(m, 2));
    m = fmaxf(m, __shfl_xor(m, 4));
    m = fmaxf(m, __shfl_xor(m, 8));
    float l = 0.f;
    #pragma unroll
    for (int j = 0; j < 4; ++j) {
        if ((j << 4) < kcap) {
            float e = (pv[j] > -1e29f) ? expf(pv[j] - m) : 0.f;
            pv[j] = e;
            l += e;
        }
    }
    l += __shfl_xor(l, 1);
    l += __shfl_xor(l, 2);
    l += __shfl_xor(l, 4);
    l += __shfl_xor(l, 8);
    float inv_l = 1.f / l;
    __syncthreads();
    float* p_s = q_s;                 // [16][65]
    #pragma unroll
    for (int j = 0; j < 4; ++j) {
        if ((j << 4) < kcap) p_s[qi * 65 + (j << 4) + g] = pv[j] * inv_l;
    }
    float* v_s = k_s;
    #pragma unroll
    for (int r = 0; r < 8; ++r) {
        int idx = tid + (r << 8);
        if (idx < (kcap << 5)) {
            int tv = idx >> 5;
            int c = idx & 31;
            size_t ro = (size_t)tv * 6144 + 4096 + (c << 2);
            float4 vs = f4sum4(base0 + ro, base1 + ro, base2 + ro, base3 + ro);
            *reinterpret_cast<float4*>(&v_s[aswz(tv, c)]) = vs;
        }
    }
    __syncthreads();
    float4 acc[2] = {{0.f,0.f,0.f,0.f},{0.f,0.f,0.f,0.f}};
    for (int ki = 0; ki < kcap; ++ki) {
        float p = p_s[qi * 65 + ki];
        #pragma unroll
        for (int u = 0; u < 2; ++u) {
            float4 vv = *reinterpret_cast<const float4*>(&v_s[aswz(ki, (g << 1) + u)]);
            acc[u].x += p * vv.x;
            acc[u].y += p * vv.y;
            acc[u].z += p * vv.z;
            acc[u].w += p * vv.w;
        }
    }
    __bf16* orow = attn_out + (size_t)(b * 64 + qg) * 2048 + h * 128 + (g << 3);
    #pragma unroll
    for (int u = 0; u < 2; ++u) {
        Pack4 p4;
        p4.h[0] = (__bf16)acc[u].x; p4.h[1] = (__bf16)acc[u].y;
        p4.h[2] = (__bf16)acc[u].z; p4.h[3] = (__bf16)acc[u].w;
        *reinterpret_cast<uint2*>(orow + (u << 2)) = p4.u;
    }
}

// ---------------------------------------------------------------------------
// 3) Outputs: sum FOUR proj partials + bias; blocks 0..8191 video broadcast
// (4 s-copies each); 8192..8319 audio. f32 normal stores.
__global__ __launch_bounds__(256) void outputs_kernel(
    const float* __restrict__ outp, const float* __restrict__ b_proj,
    float* __restrict__ d_out)
{
    const size_t PART = (size_t)256 * 2048;   // outp partial stride
    int bid = blockIdx.x;
    if (bid < 8192) {
        int which = bid >> 12;
        int rem = bid & 4095;
        int row = rem >> 6;             // b*16 + t
        int schunk = rem & 63;          // 4 s each
        int b = row >> 4;
        int t = row & 15;
        size_t srcoff = (size_t)(b * 64 + (which << 4) + t) * 2048 + threadIdx.x * 8;
        float4 s0 = f4sum4(outp + srcoff, outp + PART + srcoff,
                           outp + 2 * PART + srcoff, outp + 3 * PART + srcoff);
        float4 s1 = f4sum4(outp + srcoff + 4, outp + PART + srcoff + 4,
                           outp + 2 * PART + srcoff + 4, outp + 3 * PART + srcoff + 4);
        float4 v0 = *reinterpret_cast<const float4*>(b_proj + threadIdx.x * 8);
        float4 v1 = *reinterpret_cast<const float4*>(b_proj + threadIdx.x * 8 + 4);
        float4 o0 = {s0.x + v0.x, s0.y + v0.y, s0.z + v0.z, s0.w + v0.w};
        float4 o1 = {s1.x + v1.x, s1.y + v1.y, s1.z + v1.z, s1.w + v1.w};
        size_t base = (size_t)which * 33554432 +
                      ((size_t)row * 256 + (size_t)schunk * 4) * 2048 + threadIdx.x * 8;
        float* dst = d_out + base;
        #pragma unroll
        for (int s = 0; s < 4; ++s) {
            *reinterpret_cast<float4*>(dst + (size_t)s * 2048)     = o0;
            *reinterpret_cast<float4*>(dst + (size_t)s * 2048 + 4) = o1;
        }
    } else {
        int g8 = (bid - 8192) * 256 + threadIdx.x;  // 8-float group, 0..32767
        int which = g8 >> 14;
        int j = g8 & 16383;
        int b = j >> 12;
        int rr = j & 4095;
        int tt = rr >> 8;
        int gq = rr & 255;
        size_t srcoff = (size_t)(b * 64 + 32 + (which << 4) + tt) * 2048 + gq * 8;
        float4 s0 = f4sum4(outp + srcoff, outp + PART + srcoff,
                           outp + 2 * PART + srcoff, outp + 3 * PART + srcoff);
        float4 s1 = f4sum4(outp + srcoff + 4, outp + PART + srcoff + 4,
                           outp + 2 * PART + srcoff + 4, outp + 3 * PART + srcoff + 4);
        float4 v0 = *reinterpret_cast<const float4*>(b_proj + gq * 8);
        float4 v1 = *reinterpret_cast<const float4*>(b_proj + gq * 8 + 4);
        float4 x0 = {s0.x + v0.x, s0.y + v0.y, s0.z + v0.z, s0.w + v0.w};
        float4 x1 = {s1.x + v1.x, s1.y + v1.y, s1.z + v1.z, s1.w + v1.w};
        float* dst = d_out + 67108864 + (size_t)which * 131072 +
                     (size_t)(b * 16 + tt) * 2048 + gq * 8;
        *reinterpret_cast<float4*>(dst)     = x0;
        *reinterpret_cast<float4*>(dst + 4) = x1;
    }
}

// ---------------------------------------------------------------------------
extern "C" void kernel_launch(void* const* d_in, const int* in_sizes, int n_in,
                              void* d_out, int out_size, void* d_ws, size_t ws_size,
                              hipStream_t stream)
{
    const float* v_p    = (const float*)d_in[0];
    const float* v_f    = (const float*)d_in[1];
    const float* a_p    = (const float*)d_in[2];
    const float* a_f    = (const float*)d_in[3];
    const float* W_qkv  = (const float*)d_in[4];
    const float* W_proj = (const float*)d_in[5];
    const float* b_proj = (const float*)d_in[6];
    float* out_f = (float*)d_out;

    char* ws = (char*)d_ws;
    __bf16* tokens_bf = (__bf16*)(ws);                       // 1 MB
    __bf16* Wt_qkv    = (__bf16*)(ws + 1048576);             // 24 MB
    __bf16* Wt_proj   = (__bf16*)(ws + 26214400);            // 8 MB
    float*  qkv       = (float*)(ws + 34603008);             // 4 x 6 MB partials
    __bf16* attn_bf   = (__bf16*)(ws + 59768832);            // 1 MB
    float*  outp      = (float*)(ws + 60817408);             // 4 x 2 MB partials

    prep_all_kernel<<<4480, 256, 0, stream>>>(v_p, v_f, a_p, a_f,
                                              W_qkv, W_proj,
                                              tokens_bf, Wt_qkv, Wt_proj);
    gemm_bf16_kernel<<<dim3(96, 4, 4), 256, 0, stream>>>(tokens_bf, Wt_qkv, qkv, 6144);
    attn_kernel<<<256, 256, 0, stream>>>(qkv, attn_bf);
    gemm_bf16_kernel<<<dim3(32, 4, 4), 256, 0, stream>>>(attn_bf, Wt_proj, outp, 2048);
    outputs_kernel<<<8320, 256, 0, stream>>>(outp, b_proj, out_f);
}

// Round 20
// 196.390 us; speedup vs baseline: 1.0600x; 1.0600x over previous
//
#include <hip/hip_runtime.h>
#include <hip/hip_bf16.h>
#include <stdint.h>

// Problem: B=4, T_p=T_f=16, S=256, D=2048, H=16, hd=128, T=64 tokens.
// Inputs f32; outputs f32. GEMMs in bf16 MFMA (f32 accumulate).
// R20 = exact revert to R16 (verified 197.2us): split-K 4 GEMMs, q-quarter
// attn, 4-acc mean, 8 s-copy outputs. R19's deeper-MLP variant regressed.

using bf16x8v = __attribute__((ext_vector_type(8))) __bf16;
using f32x4v  = __attribute__((ext_vector_type(4))) float;

union Pack8 { __bf16 h[8]; uint4 u; };
union Pack4 { __bf16 h[4]; uint2 u; };

// Swizzled element offset in a [rows][64 bf16] LDS tile (GEMM):
__device__ __forceinline__ int swz(int r, int c) {
    return (r << 6) + ((c ^ (r & 7)) << 3);
}
// Swizzled float4-chunk offset in a [rows][128 f32] LDS tile (attn):
__device__ __forceinline__ int aswz(int r, int c) {
    return (r << 7) + ((c ^ (r & 31)) << 2);
}
__device__ __forceinline__ float4 f4sum4(const float* p0, const float* p1,
                                         const float* p2, const float* p3) {
    float4 a = *reinterpret_cast<const float4*>(p0);
    float4 b = *reinterpret_cast<const float4*>(p1);
    float4 c = *reinterpret_cast<const float4*>(p2);
    float4 d = *reinterpret_cast<const float4*>(p3);
    return {a.x + b.x + c.x + d.x, a.y + b.y + c.y + d.y,
            a.z + b.z + c.z + d.z, a.w + b.w + c.w + d.w};
}

// ---------------------------------------------------------------------------
// 0) Phase A, one launch (grid 4480):
//    blocks 0..255    : full-row mean -> tokens_bf rows 0..31 per batch
//    blocks 256..383  : audio pack -> tokens_bf rows 32..63 per batch
//    blocks 384..4479 : transpose+convert W_qkv / W_proj -> bf16 [N][2048]
__global__ __launch_bounds__(256) void prep_all_kernel(
    const float* __restrict__ v_p, const float* __restrict__ v_f,
    const float* __restrict__ a_p, const float* __restrict__ a_f,
    const float* __restrict__ W_qkv, const float* __restrict__ W_proj,
    __bf16* __restrict__ tokens_bf,
    __bf16* __restrict__ Wt_qkv, __bf16* __restrict__ Wt_proj)
{
    __shared__ float Ls[64][68];
    int bid0 = blockIdx.x;
    if (bid0 < 256) {
        int which  = bid0 >> 7;         // 0: v_p, 1: v_f
        int row    = (bid0 >> 1) & 63;  // b*16 + t
        int dchunk = bid0 & 1;
        int d = (dchunk << 10) + (threadIdx.x << 2);
        const float* src = (which ? v_f : v_p) + ((size_t)row << 19) + d;
        float4 a0 = {0.f,0.f,0.f,0.f}, a1 = {0.f,0.f,0.f,0.f};
        float4 a2 = {0.f,0.f,0.f,0.f}, a3 = {0.f,0.f,0.f,0.f};
        #pragma unroll 4
        for (int s = 0; s < 256; s += 4) {
            float4 x0 = *reinterpret_cast<const float4*>(src + ((size_t)(s+0) << 11));
            float4 x1 = *reinterpret_cast<const float4*>(src + ((size_t)(s+1) << 11));
            float4 x2 = *reinterpret_cast<const float4*>(src + ((size_t)(s+2) << 11));
            float4 x3 = *reinterpret_cast<const float4*>(src + ((size_t)(s+3) << 11));
            a0.x += x0.x; a0.y += x0.y; a0.z += x0.z; a0.w += x0.w;
            a1.x += x1.x; a1.y += x1.y; a1.z += x1.z; a1.w += x1.w;
            a2.x += x2.x; a2.y += x2.y; a2.z += x2.z; a2.w += x2.w;
            a3.x += x3.x; a3.y += x3.y; a3.z += x3.z; a3.w += x3.w;
        }
        const float inv = 1.f / 256.f;
        float4 o;
        o.x = (a0.x + a1.x + a2.x + a3.x) * inv;
        o.y = (a0.y + a1.y + a2.y + a3.y) * inv;
        o.z = (a0.z + a1.z + a2.z + a3.z) * inv;
        o.w = (a0.w + a1.w + a2.w + a3.w) * inv;
        int b = row >> 4, tt = row & 15;
        int tokrow = b * 64 + which * 16 + tt;
        Pack4 p4;
        p4.h[0] = (__bf16)o.x; p4.h[1] = (__bf16)o.y;
        p4.h[2] = (__bf16)o.z; p4.h[3] = (__bf16)o.w;
        *reinterpret_cast<uint2*>(&tokens_bf[(size_t)tokrow * 2048 + d]) = p4.u;
    } else if (bid0 < 384) {
        int g = (bid0 - 256) * 256 + threadIdx.x;   // 8-elem group, 0..32767
        int which = g >> 14;
        int j = g & 16383;
        int b = j >> 12;
        int rr = j & 4095;
        int tt = rr >> 8;
        int gq = rr & 255;
        const float* src = (which ? a_f : a_p) + (size_t)(b * 16 + tt) * 2048 + gq * 8;
        float4 x0 = *reinterpret_cast<const float4*>(src);
        float4 x1 = *reinterpret_cast<const float4*>(src + 4);
        Pack8 p;
        p.h[0] = (__bf16)x0.x; p.h[1] = (__bf16)x0.y; p.h[2] = (__bf16)x0.z; p.h[3] = (__bf16)x0.w;
        p.h[4] = (__bf16)x1.x; p.h[5] = (__bf16)x1.y; p.h[6] = (__bf16)x1.z; p.h[7] = (__bf16)x1.w;
        int tokrow = b * 64 + 32 + which * 16 + tt;
        *reinterpret_cast<uint4*>(&tokens_bf[(size_t)tokrow * 2048 + gq * 8]) = p.u;
    } else {
        int bid = bid0 - 384;
        const float* src; __bf16* dst; int N, tile;
        if (bid < 3072) { src = W_qkv;  dst = Wt_qkv;  N = 6144; tile = bid; }
        else            { src = W_proj; dst = Wt_proj; N = 2048; tile = bid - 3072; }
        int tiles_n = N >> 6;
        int tn = tile % tiles_n;
        int tk = tile / tiles_n;
        int t = threadIdx.x;
        int rb = t >> 4;            // 0..15
        int c4 = (t & 15) << 2;     // 0..60
        #pragma unroll
        for (int s = 0; s < 4; ++s) {
            int r = rb + (s << 4);
            float4 v = *reinterpret_cast<const float4*>(
                src + (size_t)(tk * 64 + r) * N + tn * 64 + c4);
            *reinterpret_cast<float4*>(&Ls[r][c4]) = v;
        }
        __syncthreads();
        int c  = t >> 2;            // 0..63
        int r0 = (t & 3) << 4;      // 0,16,32,48
        Pack8 p0, p1;
        #pragma unroll
        for (int i = 0; i < 8; ++i) p0.h[i] = (__bf16)Ls[r0 + i][c];
        #pragma unroll
        for (int i = 0; i < 8; ++i) p1.h[i] = (__bf16)Ls[r0 + 8 + i][c];
        __bf16* drow = dst + (size_t)(tn * 64 + c) * 2048 + tk * 64 + r0;
        *reinterpret_cast<uint4*>(drow)     = p0.u;
        *reinterpret_cast<uint4*>(drow + 8) = p1.u;
    }
}

// ---------------------------------------------------------------------------
// 1) bf16 MFMA split-K GEMM, grid.z = 4 K-quarters (8 kt each):
// Cpart[z][256][N] = A[:, z*512..] * Bt[:, z*512..]^T.
__global__ __launch_bounds__(256) void gemm_bf16_kernel(
    const __bf16* __restrict__ A, const __bf16* __restrict__ Bt,
    float* __restrict__ C, int N)
{
    __shared__ __bf16 As[4096];
    __shared__ __bf16 Bs[4096];
    const int t = threadIdx.x;
    const int m0 = blockIdx.y << 6;
    const int n0 = blockIdx.x << 6;
    const int kz = blockIdx.z;           // K-quarter 0..3
    const int kbase = kz << 9;           // element offset in K (512 each)
    const int lane = t & 63;
    const int w = t >> 6;                // wave 0..3
    const int wm = w << 4;               // wave's m offset
    const int lrow = lane & 15;
    const int lk = lane >> 4;            // 0..3
    const int srl = lane >> 3;           // 0..7
    const int schunk = lane & 7;

    f32x4v acc[4] = {{0.f,0.f,0.f,0.f},{0.f,0.f,0.f,0.f},
                     {0.f,0.f,0.f,0.f},{0.f,0.f,0.f,0.f}};

    int row_c0 = (w << 4) + srl;
    int row_c1 = row_c0 + 8;
    const __bf16* gA0 = A  + (size_t)(m0 + row_c0) * 2048 + kbase + ((schunk ^ (row_c0 & 7)) << 3);
    const __bf16* gA1 = A  + (size_t)(m0 + row_c1) * 2048 + kbase + ((schunk ^ (row_c1 & 7)) << 3);
    const __bf16* gB0 = Bt + (size_t)(n0 + row_c0) * 2048 + kbase + ((schunk ^ (row_c0 & 7)) << 3);
    const __bf16* gB1 = Bt + (size_t)(n0 + row_c1) * 2048 + kbase + ((schunk ^ (row_c1 & 7)) << 3);
    __bf16* lA0 = &As[(w << 4) << 6];
    __bf16* lA1 = &As[((w << 4) + 8) << 6];
    __bf16* lB0 = &Bs[(w << 4) << 6];
    __bf16* lB1 = &Bs[((w << 4) + 8) << 6];

    for (int kt = 0; kt < 8; ++kt) {
        __syncthreads();
        int ko = kt << 6;
        __builtin_amdgcn_global_load_lds(
            (const __attribute__((address_space(1))) void*)(gA0 + ko),
            (__attribute__((address_space(3))) void*)lA0, 16, 0, 0);
        __builtin_amdgcn_global_load_lds(
            (const __attribute__((address_space(1))) void*)(gA1 + ko),
            (__attribute__((address_space(3))) void*)lA1, 16, 0, 0);
        __builtin_amdgcn_global_load_lds(
            (const __attribute__((address_space(1))) void*)(gB0 + ko),
            (__attribute__((address_space(3))) void*)lB0, 16, 0, 0);
        __builtin_amdgcn_global_load_lds(
            (const __attribute__((address_space(1))) void*)(gB1 + ko),
            (__attribute__((address_space(3))) void*)lB1, 16, 0, 0);
        __syncthreads();
        #pragma unroll
        for (int s = 0; s < 2; ++s) {
            int cA = (s << 2) + lk;
            bf16x8v af = *reinterpret_cast<const bf16x8v*>(&As[swz(wm + lrow, cA)]);
            #pragma unroll
            for (int j = 0; j < 4; ++j) {
                bf16x8v bf = *reinterpret_cast<const bf16x8v*>(&Bs[swz((j << 4) + lrow, cA)]);
                acc[j] = __builtin_amdgcn_mfma_f32_16x16x32_bf16(af, bf, acc[j], 0, 0, 0);
            }
        }
    }
    float* Cz = C + (size_t)kz * 256 * N;
    #pragma unroll
    for (int j = 0; j < 4; ++j) {
        int col = n0 + (j << 4) + lrow;
        #pragma unroll
        for (int e = 0; e < 4; ++e) {
            int row = m0 + wm + (lk << 2) + e;
            Cz[(size_t)row * N + col] = acc[j][e];
        }
    }
}

// ---------------------------------------------------------------------------
// 2) Attention: block = (b, h, q-quarter of 16 rows), grid 256. Sums the
// FOUR qkv K-partials during staging, RoPE after sum; causal softmax; bf16
// out. Static-indexed registers; uniform guards.
__global__ __launch_bounds__(256) void attn_kernel(
    const float* __restrict__ qkv, __bf16* __restrict__ attn_out)
{
    __shared__ float q_s[16 * 128];   // 8KB swizzled; reused as p_s[16][65]
    __shared__ float k_s[64 * 128];   // 32KB swizzled; reused as v_s
    const size_t PART = (size_t)256 * 6144;   // qkv partial stride
    int bid = blockIdx.x;
    int qt = bid & 3;                 // q-quarter
    int h  = (bid >> 2) & 15;
    int b  = bid >> 6;
    int tid = threadIdx.x;
    int qr0 = qt << 4;                // first q row of this block
    int kcap = qr0 + 16;              // causal K rows needed (16/32/48/64)
    const float* base0 = qkv + (size_t)(b * 64) * 6144 + h * 128;
    const float* base1 = base0 + PART;
    const float* base2 = base0 + 2 * PART;
    const float* base3 = base0 + 3 * PART;
    const float L2C = 0.20762050593046012f;   // log2(10000)/64
    const float scale = 0.0883883476483184405f;   // 128^-0.5

    {
        int tq = tid >> 4;            // local row 0..15
        int cg = tid & 15;            // low-half chunk
        int d = cg << 2;
        int grow = qr0 + tq;
        size_t ro = (size_t)grow * 6144;
        float4 q1 = f4sum4(base0 + ro + d, base1 + ro + d, base2 + ro + d, base3 + ro + d);
        float4 q2 = f4sum4(base0 + ro + d + 64, base1 + ro + d + 64,
                           base2 + ro + d + 64, base3 + ro + d + 64);
        float ft = (float)grow;
        float a0 = ft * exp2f(-(float)(d + 0) * L2C);
        float a1 = ft * exp2f(-(float)(d + 1) * L2C);
        float a2 = ft * exp2f(-(float)(d + 2) * L2C);
        float a3 = ft * exp2f(-(float)(d + 3) * L2C);
        float c0 = cosf(a0), s0f = sinf(a0);
        float c1 = cosf(a1), s1f = sinf(a1);
        float c2 = cosf(a2), s2f = sinf(a2);
        float c3 = cosf(a3), s3f = sinf(a3);
        float4 qa, qb;
        qa.x = q1.x * c0 - q2.x * s0f;  qb.x = q2.x * c0 + q1.x * s0f;
        qa.y = q1.y * c1 - q2.y * s1f;  qb.y = q2.y * c1 + q1.y * s1f;
        qa.z = q1.z * c2 - q2.z * s2f;  qb.z = q2.z * c2 + q1.z * s2f;
        qa.w = q1.w * c3 - q2.w * s3f;  qb.w = q2.w * c3 + q1.w * s3f;
        *reinterpret_cast<float4*>(&q_s[aswz(tq, cg)])      = qa;
        *reinterpret_cast<float4*>(&q_s[aswz(tq, cg + 16)]) = qb;
    }
    #pragma unroll
    for (int r = 0; r < 4; ++r) {
        int idx = tid + (r << 8);
        if (idx < (kcap << 4)) {
            int tk = idx >> 4;        // global k row
            int cg = idx & 15;
            int d = cg << 2;
            size_t ro = (size_t)tk * 6144 + 2048;
            float4 k1 = f4sum4(base0 + ro + d, base1 + ro + d, base2 + ro + d, base3 + ro + d);
            float4 k2 = f4sum4(base0 + ro + d + 64, base1 + ro + d + 64,
                               base2 + ro + d + 64, base3 + ro + d + 64);
            float ft = (float)tk;
            float a0 = ft * exp2f(-(float)(d + 0) * L2C);
            float a1 = ft * exp2f(-(float)(d + 1) * L2C);
            float a2 = ft * exp2f(-(float)(d + 2) * L2C);
            float a3 = ft * exp2f(-(float)(d + 3) * L2C);
            float c0 = cosf(a0), s0f = sinf(a0);
            float c1 = cosf(a1), s1f = sinf(a1);
            float c2 = cosf(a2), s2f = sinf(a2);
            float c3 = cosf(a3), s3f = sinf(a3);
            float4 ka, kb;
            ka.x = k1.x * c0 - k2.x * s0f;  kb.x = k2.x * c0 + k1.x * s0f;
            ka.y = k1.y * c1 - k2.y * s1f;  kb.y = k2.y * c1 + k1.y * s1f;
            ka.z = k1.z * c2 - k2.z * s2f;  kb.z = k2.z * c2 + k1.z * s2f;
            ka.w = k1.w * c3 - k2.w * s3f;  kb.w = k2.w * c3 + k1.w * s3f;
            *reinterpret_cast<float4*>(&k_s[aswz(tk, cg)])      = ka;
            *reinterpret_cast<float4*>(&k_s[aswz(tk, cg + 16)]) = kb;
        }
    }
    __syncthreads();
    int qi = tid >> 4;
    int g  = tid & 15;
    int qg = qr0 + qi;
    float pv[4] = {0.f, 0.f, 0.f, 0.f};
    for (int c = 0; c < 32; ++c) {
        float4 a = *reinterpret_cast<const float4*>(&q_s[aswz(qi, c)]);
        #pragma unroll
        for (int j = 0; j < 4; ++j) {
            if ((j << 4) < kcap) {
                int ki = (j << 4) + g;
                float4 bb = *reinterpret_cast<const float4*>(&k_s[aswz(ki, c)]);
                pv[j] += a.x * bb.x + a.y * bb.y + a.z * bb.z + a.w * bb.w;
            }
        }
    }
    float m = -1e30f;
    #pragma unroll
    for (int j = 0; j < 4; ++j) {
        if ((j << 4) < kcap) {
            int ki = (j << 4) + g;
            pv[j] = (ki <= qg) ? pv[j] * scale : -1e30f;
            m = fmaxf(m, pv[j]);
        }
    }
    m = fmaxf(m, __shfl_xor(m, 1));
    m = fmaxf(m, __shfl_xor(m, 2));
    m = fmaxf(m, __shfl_xor(m, 4));
    m = fmaxf(m, __shfl_xor(m, 8));
    float l = 0.f;
    #pragma unroll
    for (int j = 0; j < 4; ++j) {
        if ((j << 4) < kcap) {
            float e = (pv[j] > -1e29f) ? expf(pv[j] - m) : 0.f;
            pv[j] = e;
            l += e;
        }
    }
    l += __shfl_xor(l, 1);
    l += __shfl_xor(l, 2);
    l += __shfl_xor(l, 4);
    l += __shfl_xor(l, 8);
    float inv_l = 1.f / l;
    __syncthreads();
    float* p_s = q_s;                 // [16][65]
    #pragma unroll
    for (int j = 0; j < 4; ++j) {
        if ((j << 4) < kcap) p_s[qi * 65 + (j << 4) + g] = pv[j] * inv_l;
    }
    float* v_s = k_s;
    #pragma unroll
    for (int r = 0; r < 8; ++r) {
        int idx = tid + (r << 8);
        if (idx < (kcap << 5)) {
            int tv = idx >> 5;
            int c = idx & 31;
            size_t ro = (size_t)tv * 6144 + 4096 + (c << 2);
            float4 vs = f4sum4(base0 + ro, base1 + ro, base2 + ro, base3 + ro);
            *reinterpret_cast<float4*>(&v_s[aswz(tv, c)]) = vs;
        }
    }
    __syncthreads();
    float4 acc[2] = {{0.f,0.f,0.f,0.f},{0.f,0.f,0.f,0.f}};
    for (int ki = 0; ki < kcap; ++ki) {
        float p = p_s[qi * 65 + ki];
        #pragma unroll
        for (int u = 0; u < 2; ++u) {
            float4 vv = *reinterpret_cast<const float4*>(&v_s[aswz(ki, (g << 1) + u)]);
            acc[u].x += p * vv.x;
            acc[u].y += p * vv.y;
            acc[u].z += p * vv.z;
            acc[u].w += p * vv.w;
        }
    }
    __bf16* orow = attn_out + (size_t)(b * 64 + qg) * 2048 + h * 128 + (g << 3);
    #pragma unroll
    for (int u = 0; u < 2; ++u) {
        Pack4 p4;
        p4.h[0] = (__bf16)acc[u].x; p4.h[1] = (__bf16)acc[u].y;
        p4.h[2] = (__bf16)acc[u].z; p4.h[3] = (__bf16)acc[u].w;
        *reinterpret_cast<uint2*>(orow + (u << 2)) = p4.u;
    }
}

// ---------------------------------------------------------------------------
// 3) Outputs: sum FOUR proj partials + bias; blocks 0..4095 video broadcast
// (8 s-copies); 4096..4223 audio. f32 normal stores.
__global__ __launch_bounds__(256) void outputs_kernel(
    const float* __restrict__ outp, const float* __restrict__ b_proj,
    float* __restrict__ d_out)
{
    const size_t PART = (size_t)256 * 2048;   // outp partial stride
    int bid = blockIdx.x;
    if (bid < 4096) {
        int which = bid >> 11;
        int rem = bid & 2047;
        int row = rem >> 5;             // b*16 + t
        int schunk = rem & 31;          // 8 s each
        int b = row >> 4;
        int t = row & 15;
        size_t srcoff = (size_t)(b * 64 + (which << 4) + t) * 2048 + threadIdx.x * 8;
        float4 s0 = f4sum4(outp + srcoff, outp + PART + srcoff,
                           outp + 2 * PART + srcoff, outp + 3 * PART + srcoff);
        float4 s1 = f4sum4(outp + srcoff + 4, outp + PART + srcoff + 4,
                           outp + 2 * PART + srcoff + 4, outp + 3 * PART + srcoff + 4);
        float4 v0 = *reinterpret_cast<const float4*>(b_proj + threadIdx.x * 8);
        float4 v1 = *reinterpret_cast<const float4*>(b_proj + threadIdx.x * 8 + 4);
        float4 o0 = {s0.x + v0.x, s0.y + v0.y, s0.z + v0.z, s0.w + v0.w};
        float4 o1 = {s1.x + v1.x, s1.y + v1.y, s1.z + v1.z, s1.w + v1.w};
        size_t base = (size_t)which * 33554432 +
                      ((size_t)row * 256 + (size_t)schunk * 8) * 2048 + threadIdx.x * 8;
        float* dst = d_out + base;
        #pragma unroll
        for (int s = 0; s < 8; ++s) {
            *reinterpret_cast<float4*>(dst + (size_t)s * 2048)     = o0;
            *reinterpret_cast<float4*>(dst + (size_t)s * 2048 + 4) = o1;
        }
    } else {
        int g8 = (bid - 4096) * 256 + threadIdx.x;  // 8-float group, 0..32767
        int which = g8 >> 14;
        int j = g8 & 16383;
        int b = j >> 12;
        int rr = j & 4095;
        int tt = rr >> 8;
        int gq = rr & 255;
        size_t srcoff = (size_t)(b * 64 + 32 + (which << 4) + tt) * 2048 + gq * 8;
        float4 s0 = f4sum4(outp + srcoff, outp + PART + srcoff,
                           outp + 2 * PART + srcoff, outp + 3 * PART + srcoff);
        float4 s1 = f4sum4(outp + srcoff + 4, outp + PART + srcoff + 4,
                           outp + 2 * PART + srcoff + 4, outp + 3 * PART + srcoff + 4);
        float4 v0 = *reinterpret_cast<const float4*>(b_proj + gq * 8);
        float4 v1 = *reinterpret_cast<const float4*>(b_proj + gq * 8 + 4);
        float4 x0 = {s0.x + v0.x, s0.y + v0.y, s0.z + v0.z, s0.w + v0.w};
        float4 x1 = {s1.x + v1.x, s1.y + v1.y, s1.z + v1.z, s1.w + v1.w};
        float* dst = d_out + 67108864 + (size_t)which * 131072 +
                     (size_t)(b * 16 + tt) * 2048 + gq * 8;
        *reinterpret_cast<float4*>(dst)     = x0;
        *reinterpret_cast<float4*>(dst + 4) = x1;
    }
}

// ---------------------------------------------------------------------------
extern "C" void kernel_launch(void* const* d_in, const int* in_sizes, int n_in,
                              void* d_out, int out_size, void* d_ws, size_t ws_size,
                              hipStream_t stream)
{
    const float* v_p    = (const float*)d_in[0];
    const float* v_f    = (const float*)d_in[1];
    const float* a_p    = (const float*)d_in[2];
    const float* a_f    = (const float*)d_in[3];
    const float* W_qkv  = (const float*)d_in[4];
    const float* W_proj = (const float*)d_in[5];
    const float* b_proj = (const float*)d_in[6];
    float* out_f = (float*)d_out;

    char* ws = (char*)d_ws;
    __bf16* tokens_bf = (__bf16*)(ws);                       // 1 MB
    __bf16* Wt_qkv    = (__bf16*)(ws + 1048576);             // 24 MB
    __bf16* Wt_proj   = (__bf16*)(ws + 26214400);            // 8 MB
    float*  qkv       = (float*)(ws + 34603008);             // 4 x 6 MB partials
    __bf16* attn_bf   = (__bf16*)(ws + 59768832);            // 1 MB
    float*  outp      = (float*)(ws + 60817408);             // 4 x 2 MB partials

    prep_all_kernel<<<4480, 256, 0, stream>>>(v_p, v_f, a_p, a_f,
                                              W_qkv, W_proj,
                                              tokens_bf, Wt_qkv, Wt_proj);
    gemm_bf16_kernel<<<dim3(96, 4, 4), 256, 0, stream>>>(tokens_bf, Wt_qkv, qkv, 6144);
    attn_kernel<<<256, 256, 0, stream>>>(qkv, attn_bf);
    gemm_bf16_kernel<<<dim3(32, 4, 4), 256, 0, stream>>>(attn_bf, Wt_proj, outp, 2048);
    outputs_kernel<<<4224, 256, 0, stream>>>(outp, b_proj, out_f);
}